// Round 3
// baseline (553.190 us; speedup 1.0000x reference)
//
#include <hip/hip_runtime.h>
#include <cstdint>
#include <cstddef>

// Binarized basic block on MI355X.
// |acc| <= 9*128 = 1152 < THRESH=8000, so the per-partial-sum clip never
// binds -> both convs are exact int convolutions of sign() values.
// int8 implicit GEMM via mfma_i32_16x16x64_i8; all float ops bit-exact vs
// numpy fp32 (explicit __fmul_rn/__fadd_rn, no FMA contraction).
//
// R3: persistent conv blocks (grid=256, 1/CU), ALL weights resident in LDS
// (144 KB, gfx950 has 160 KB/WG) -> barrier-free K-loop with 32 MFMAs per
// 8 ds_read_b128. O-channel mapping o = col*8 + n so each lane owns 8
// CONTIGUOUS output channels -> full-line dwordx2 sign stores (kills the
// 4.6x write amplification seen in R2) and float4 phase-2 epilogue.
// prep_x writes through an LDS transpose for full-line stores.

typedef int      v4i __attribute__((ext_vector_type(4)));
typedef float    v4f __attribute__((ext_vector_type(4)));
typedef unsigned int v2u __attribute__((ext_vector_type(2)));

constexpr int B = 64, C = 128, H = 56, W = 56;
constexpr int HP = H + 2, WP = W + 2;      // zero-padded spatial
constexpr int PIX = H * W;                 // 3136
constexpr int M = B * H * W;               // 200704 = 784 * 256
constexpr int NTILES = M / 256;            // 784

// workspace layout (bytes)
constexpr size_t XS_BYTES = (size_t)B * HP * WP * C;   // 27,557,888
constexpr size_t XS1_OFF = 0;
constexpr size_t XS2_OFF = XS_BYTES;
constexpr size_t WF_BYTES = 18 * 8192;                 // 147,456
constexpr size_t WF1_OFF = 2 * XS_BYTES;
constexpr size_t WF2_OFF = WF1_OFF + WF_BYTES;
constexpr size_t BNP_OFF = WF2_OFF + WF_BYTES;         // 4*128 floats

// ---------------------------------------------------------------------------
// Zero only the padded halos of xs1/xs2 (interiors are fully overwritten).
__global__ __launch_bounds__(256) void zero_halo(int8_t* __restrict__ xs1,
                                                 int8_t* __restrict__ xs2) {
    int b = blockIdx.x;
    int t = threadIdx.x;
    size_t ib = (size_t)b * HP * WP * C;
#pragma unroll
    for (int a = 0; a < 2; ++a) {
        uint32_t* p = (uint32_t*)((a ? xs2 : xs1) + ib);
        const int ROWD = WP * C / 4;             // 1856 dwords per padded row
        for (int i = t; i < ROWD; i += 256) {
            p[i] = 0;
            p[(HP - 1) * ROWD + i] = 0;
        }
        for (int i = t; i < 56 * 2 * 32; i += 256) {
            int r = i >> 6;
            int side = (i >> 5) & 1;
            int j = i & 31;
            p[((r + 1) * WP + side * (WP - 1)) * (C / 4) + j] = 0;
        }
    }
}

// ---------------------------------------------------------------------------
// sign(x) -> padded NHWC int8, via LDS transpose so global stores are
// 16 B/lane full-line. Block = 256 threads = 256 pixels.
__global__ __launch_bounds__(256) void prep_x(const float* __restrict__ x,
                                              int8_t* __restrict__ xs) {
    __shared__ uint32_t tl[256 * 33];   // +1 dword pad -> conflict-free writes
    int t = threadIdx.x;
    int m = blockIdx.x * 256 + t;
    int b_ = m / PIX, hw = m % PIX;
    const float* xp = x + (size_t)b_ * C * PIX + hw;
#pragma unroll
    for (int c4 = 0; c4 < 32; ++c4) {
        uint32_t v = 0;
#pragma unroll
        for (int j = 0; j < 4; ++j) {
            float f = xp[(size_t)(c4 * 4 + j) * PIX];
            v |= ((uint32_t)(uint8_t)(int8_t)((f > 0.f) - (f < 0.f))) << (8 * j);
        }
        tl[t * 33 + c4] = v;
    }
    __syncthreads();
    int pl = t >> 3, co = t & 7;        // 8 threads per pixel, 16 B each
#pragma unroll
    for (int pass = 0; pass < 8; ++pass) {
        int p = pass * 32 + pl;
        int mg = blockIdx.x * 256 + p;
        int b2 = mg / PIX, hw2 = mg % PIX, h2 = hw2 / W, w2 = hw2 % W;
        size_t ob = ((size_t)(b2 * HP + h2 + 1) * WP + (w2 + 1)) * C + co * 16;
        v4i val;
#pragma unroll
        for (int k = 0; k < 4; ++k) val[k] = (int)tl[p * 33 + co * 4 + k];
        *(v4i*)(xs + ob) = val;
    }
}

// ---------------------------------------------------------------------------
// Binarize weights into MFMA B-fragment order with o = col*8 + n:
//   wf[((tap*2+kh)*8+n)*1024 + lane*16 + j] =
//     sign(w[o=(lane&15)*8+n][c=kh*64+(lane>>4)*16+j][r][s])
// Also BN inv/shift tables exactly as numpy fp32.
__global__ __launch_bounds__(256) void prep_w(
    const float* __restrict__ w1, const float* __restrict__ w2,
    const float* __restrict__ g1, const float* __restrict__ be1,
    const float* __restrict__ mu1, const float* __restrict__ va1,
    const float* __restrict__ g2, const float* __restrict__ be2,
    const float* __restrict__ mu2, const float* __restrict__ va2,
    int8_t* __restrict__ wf1, int8_t* __restrict__ wf2,
    float* __restrict__ bnp) {
    int t = blockIdx.x * 256 + threadIdx.x;
    if (t < 256) {
        int o = t & 127;
        if (t < 128) {
            float inv = g1[o] / sqrtf(va1[o] + 1e-5f);
            bnp[o]       = inv;
            bnp[128 + o] = __fsub_rn(be1[o], __fmul_rn(mu1[o], inv));
        } else {
            float inv = g2[o] / sqrtf(va2[o] + 1e-5f);
            bnp[256 + o] = inv;
            bnp[384 + o] = __fsub_rn(be2[o], __fmul_rn(mu2[o], inv));
        }
    }
    if (t >= 2 * 18 * 8 * 64) return;
    int lane = t & 63;
    int nsub = (t >> 6) & 7;
    int kh   = (t >> 9) & 1;
    int tap  = (t >> 10) % 9;
    int which = (t >> 10) / 9;
    const float* w = which ? w2 : w1;
    int8_t* wf = which ? wf2 : wf1;
    int o = (lane & 15) * 8 + nsub;          // R3: lane-contiguous O mapping
    int cbase = kh * 64 + (lane >> 4) * 16;
    int r = tap / 3, s = tap % 3;
    int8_t frag[16];
#pragma unroll
    for (int j = 0; j < 16; ++j) {
        float f = w[((size_t)(o * C + cbase + j) * 3 + r) * 3 + s];
        frag[j] = (int8_t)((f > 0.f) - (f < 0.f));
    }
    *(v4i*)(wf + (size_t)(((tap * 2 + kh) * 8 + nsub) * 64 + lane) * 16) =
        *(const v4i*)frag;
}

// ---------------------------------------------------------------------------
// Persistent binary conv. Grid = 256 blocks (1/CU), 256 thr (4 waves).
// All 18*8KB weights staged to LDS once; then grid-stride over 256-row
// M-tiles. Each wave owns 64 rows (4 row-groups x 8 O-tiles = 32 accs).
// K-loop: 18 steps, per step 8 ds_read_b128 + 32 MFMAs, A prefetched one
// step ahead. NO barriers, NO global weight traffic in the loop.
// PHASE 1: sign(BN1(conv)) -> padded NHWC int8 (8 contiguous bytes/lane).
// PHASE 2: clip(BN2(conv) + residual, -1, 1) -> NCHW fp32 (float4 I/O).
template <int PHASE>
__global__ __launch_bounds__(256) void conv_bin(
    const int8_t* __restrict__ xs,
    const int8_t* __restrict__ wf,
    const float* __restrict__ bnp,
    const float* __restrict__ xres,
    int8_t* __restrict__ xs_next,
    float* __restrict__ out)
{
    __shared__ int8_t wlds[18 * 8192];       // 147,456 B (gfx950: 160K/WG)
    int t = threadIdx.x, lane = t & 63, wv = t >> 6;
    int quad = lane >> 4, l15 = lane & 15;

    // one-time weight staging (coalesced 16 B/lane, 36 iters/thread)
    {
        const v4i* g = (const v4i*)wf;
        v4i* l = (v4i*)wlds;
        for (int i = t; i < 18 * 512; i += 256) l[i] = g[i];
    }
    // BN params for this lane's 8 contiguous output channels o = l15*8+n
    float binv[8], btt[8];
    {
        int o0 = (PHASE == 1 ? 0 : 256) + l15 * 8;
        int o1 = (PHASE == 1 ? 128 : 384) + l15 * 8;
#pragma unroll
        for (int n = 0; n < 8; ++n) { binv[n] = bnp[o0 + n]; btt[n] = bnp[o1 + n]; }
    }
    __syncthreads();

    for (int tile = blockIdx.x; tile < NTILES; tile += gridDim.x) {
        int mwave = tile * 256 + wv * 64;
        size_t abase[4];
#pragma unroll
        for (int rg = 0; rg < 4; ++rg) {
            int ma = mwave + rg * 16 + l15;
            int wa = ma % W; int ta = ma / W; int ha = ta % H; int ba = ta / H;
            abase[rg] = ((size_t)(ba * HP + ha) * WP + wa) * C + (size_t)quad * 16;
        }

        v4i acc[4][8];
#pragma unroll
        for (int rg = 0; rg < 4; ++rg)
#pragma unroll
            for (int n = 0; n < 8; ++n) acc[rg][n] = (v4i)0;

        v4i a[4];
#pragma unroll
        for (int rg = 0; rg < 4; ++rg) a[rg] = *(const v4i*)(xs + abase[rg]);

#pragma unroll
        for (int step = 0; step < 18; ++step) {
            v4i an[4];
            if (step + 1 < 18) {
                int nt = (step + 1) >> 1, nk = (step + 1) & 1;
                size_t aoff = (size_t)((nt / 3) * WP + (nt % 3)) * C + nk * 64;
#pragma unroll
                for (int rg = 0; rg < 4; ++rg)
                    an[rg] = *(const v4i*)(xs + abase[rg] + aoff);
            }
            const int8_t* lb = wlds + step * 8192;
#pragma unroll
            for (int n = 0; n < 8; ++n) {
                v4i bf = *(const v4i*)(lb + ((n * 64 + lane) << 4));
#pragma unroll
                for (int rg = 0; rg < 4; ++rg)
                    acc[rg][n] = __builtin_amdgcn_mfma_i32_16x16x64_i8(
                        a[rg], bf, acc[rg][n], 0, 0, 0);
            }
            if (step + 1 < 18) {
#pragma unroll
                for (int rg = 0; rg < 4; ++rg) a[rg] = an[rg];
            }
        }

        // Epilogue. D layout: col = l15 (-> o = l15*8+n), row = quad*4 + i.
#pragma unroll
        for (int rg = 0; rg < 4; ++rg) {
            int m0 = mwave + rg * 16 + quad * 4;     // multiple of 4; W%4==0
            int w0 = m0 % W; int t0 = m0 / W; int h0 = t0 % H; int b0 = t0 / H;
            if (PHASE == 1) {
                size_t base = ((size_t)(b0 * HP + h0 + 1) * WP + (w0 + 1)) * C
                              + (size_t)l15 * 8;
#pragma unroll
                for (int i = 0; i < 4; ++i) {
                    uint32_t lo = 0, hi = 0;
#pragma unroll
                    for (int n = 0; n < 8; ++n) {
                        float y = __fadd_rn(__fmul_rn((float)acc[rg][n][i], binv[n]), btt[n]);
                        uint32_t sb = (uint8_t)(int8_t)((y > 0.f) - (y < 0.f));
                        if (n < 4) lo |= sb << (8 * n);
                        else       hi |= sb << (8 * (n - 4));
                    }
                    v2u pk; pk[0] = lo; pk[1] = hi;
                    *(v2u*)(xs_next + base + (size_t)i * C) = pk;
                }
            } else {
                size_t pixb = (size_t)b0 * C * PIX + h0 * W + w0;
                v4f r[8];
#pragma unroll
                for (int n = 0; n < 8; ++n)
                    r[n] = *(const v4f*)(xres + pixb + (size_t)(l15 * 8 + n) * PIX);
#pragma unroll
                for (int n = 0; n < 8; ++n) {
                    size_t idx = pixb + (size_t)(l15 * 8 + n) * PIX;
                    v4f z;
#pragma unroll
                    for (int i = 0; i < 4; ++i) {
                        float y = __fadd_rn(__fmul_rn((float)acc[rg][n][i], binv[n]), btt[n]);
                        float v = __fadd_rn(y, r[n][i]);
                        z[i] = fminf(fmaxf(v, -1.f), 1.f);
                    }
                    *(v4f*)(out + idx) = z;
                }
            }
        }
    }
}

// ---------------------------------------------------------------------------
extern "C" void kernel_launch(void* const* d_in, const int* in_sizes, int n_in,
                              void* d_out, int out_size, void* d_ws, size_t ws_size,
                              hipStream_t stream) {
    const float* x   = (const float*)d_in[0];
    const float* w1  = (const float*)d_in[1];
    const float* w2  = (const float*)d_in[2];
    const float* g1  = (const float*)d_in[3];
    const float* be1 = (const float*)d_in[4];
    const float* mu1 = (const float*)d_in[5];
    const float* va1 = (const float*)d_in[6];
    const float* g2  = (const float*)d_in[7];
    const float* be2 = (const float*)d_in[8];
    const float* mu2 = (const float*)d_in[9];
    const float* va2 = (const float*)d_in[10];

    int8_t* ws  = (int8_t*)d_ws;
    int8_t* xs1 = ws + XS1_OFF;
    int8_t* xs2 = ws + XS2_OFF;
    int8_t* wf1 = ws + WF1_OFF;
    int8_t* wf2 = ws + WF2_OFF;
    float*  bnp = (float*)(ws + BNP_OFF);

    zero_halo<<<B, 256, 0, stream>>>(xs1, xs2);
    prep_x<<<M / 256, 256, 0, stream>>>(x, xs1);
    prep_w<<<(2 * 18 * 8 * 64 + 255) / 256, 256, 0, stream>>>(
        w1, w2, g1, be1, mu1, va1, g2, be2, mu2, va2, wf1, wf2, bnp);

    conv_bin<1><<<256, 256, 0, stream>>>(xs1, wf1, bnp, nullptr, xs2, nullptr);
    conv_bin<2><<<256, 256, 0, stream>>>(xs2, wf2, bnp, x, nullptr, (float*)d_out);
}

// Round 4
// 538.887 us; speedup vs baseline: 1.0265x; 1.0265x over previous
//
#include <hip/hip_runtime.h>
#include <cstdint>
#include <cstddef>

// Binarized basic block on MI355X.
// |acc| <= 9*128 = 1152 < THRESH=8000, so the per-partial-sum clip never
// binds -> both convs are exact int convolutions of sign() values.
// int8 implicit GEMM via mfma_i32_16x16x64_i8; all float ops bit-exact vs
// numpy fp32 (explicit __fmul_rn/__fadd_rn, no FMA contraction).
//
// R4: R3 structure (persistent blocks, ALL weights LDS-resident, barrier-free
// K-loop, contiguous-O full-line stores) with the R3 failure modes fixed:
//  - __launch_bounds__(256,1): LDS already caps us at 1 wave/SIMD, so give
//    the allocator the full unified 512-reg file -> no scratch spills
//    (R3: VGPR=256 cap -> ~190 MB spill traffic per conv).
//  - XCD-aware tile swizzle: 784 tiles = 8 XCDs x 98; each XCD works a
//    contiguous 3.2 MB xs slice that fits its 4 MB L2 -> 9x tap re-reads
//    become L2-local instead of cross-XCD thrash.

typedef int      v4i __attribute__((ext_vector_type(4)));
typedef float    v4f __attribute__((ext_vector_type(4)));
typedef unsigned int v2u __attribute__((ext_vector_type(2)));

constexpr int B = 64, C = 128, H = 56, W = 56;
constexpr int HP = H + 2, WP = W + 2;      // zero-padded spatial
constexpr int PIX = H * W;                 // 3136
constexpr int M = B * H * W;               // 200704 = 784 * 256
constexpr int NTILES = M / 256;            // 784 tiles of 256 rows
constexpr int TPX = NTILES / 8;            // 98 tiles per XCD

// workspace layout (bytes)
constexpr size_t XS_BYTES = (size_t)B * HP * WP * C;   // 27,557,888
constexpr size_t XS1_OFF = 0;
constexpr size_t XS2_OFF = XS_BYTES;
constexpr size_t WF_BYTES = 18 * 8192;                 // 147,456
constexpr size_t WF1_OFF = 2 * XS_BYTES;
constexpr size_t WF2_OFF = WF1_OFF + WF_BYTES;
constexpr size_t BNP_OFF = WF2_OFF + WF_BYTES;         // 4*128 floats

// ---------------------------------------------------------------------------
// Zero only the padded halos of xs1/xs2 (interiors are fully overwritten).
__global__ __launch_bounds__(256) void zero_halo(int8_t* __restrict__ xs1,
                                                 int8_t* __restrict__ xs2) {
    int b = blockIdx.x;
    int t = threadIdx.x;
    size_t ib = (size_t)b * HP * WP * C;
#pragma unroll
    for (int a = 0; a < 2; ++a) {
        uint32_t* p = (uint32_t*)((a ? xs2 : xs1) + ib);
        const int ROWD = WP * C / 4;             // 1856 dwords per padded row
        for (int i = t; i < ROWD; i += 256) {
            p[i] = 0;
            p[(HP - 1) * ROWD + i] = 0;
        }
        for (int i = t; i < 56 * 2 * 32; i += 256) {
            int r = i >> 6;
            int side = (i >> 5) & 1;
            int j = i & 31;
            p[((r + 1) * WP + side * (WP - 1)) * (C / 4) + j] = 0;
        }
    }
}

// ---------------------------------------------------------------------------
// sign(x) -> padded NHWC int8, via LDS transpose so global stores are
// 16 B/lane full-line. Block = 256 threads = 256 pixels.
__global__ __launch_bounds__(256) void prep_x(const float* __restrict__ x,
                                              int8_t* __restrict__ xs) {
    __shared__ uint32_t tl[256 * 33];   // +1 dword pad -> conflict-free writes
    int t = threadIdx.x;
    int m = blockIdx.x * 256 + t;
    int b_ = m / PIX, hw = m % PIX;
    const float* xp = x + (size_t)b_ * C * PIX + hw;
#pragma unroll
    for (int c4 = 0; c4 < 32; ++c4) {
        uint32_t v = 0;
#pragma unroll
        for (int j = 0; j < 4; ++j) {
            float f = xp[(size_t)(c4 * 4 + j) * PIX];
            v |= ((uint32_t)(uint8_t)(int8_t)((f > 0.f) - (f < 0.f))) << (8 * j);
        }
        tl[t * 33 + c4] = v;
    }
    __syncthreads();
    int pl = t >> 3, co = t & 7;        // 8 threads per pixel, 16 B each
#pragma unroll
    for (int pass = 0; pass < 8; ++pass) {
        int p = pass * 32 + pl;
        int mg = blockIdx.x * 256 + p;
        int b2 = mg / PIX, hw2 = mg % PIX, h2 = hw2 / W, w2 = hw2 % W;
        size_t ob = ((size_t)(b2 * HP + h2 + 1) * WP + (w2 + 1)) * C + co * 16;
        v4i val;
#pragma unroll
        for (int k = 0; k < 4; ++k) val[k] = (int)tl[p * 33 + co * 4 + k];
        *(v4i*)(xs + ob) = val;
    }
}

// ---------------------------------------------------------------------------
// Binarize weights into MFMA B-fragment order with o = col*8 + n:
//   wf[((tap*2+kh)*8+n)*1024 + lane*16 + j] =
//     sign(w[o=(lane&15)*8+n][c=kh*64+(lane>>4)*16+j][r][s])
// Also BN inv/shift tables exactly as numpy fp32.
__global__ __launch_bounds__(256) void prep_w(
    const float* __restrict__ w1, const float* __restrict__ w2,
    const float* __restrict__ g1, const float* __restrict__ be1,
    const float* __restrict__ mu1, const float* __restrict__ va1,
    const float* __restrict__ g2, const float* __restrict__ be2,
    const float* __restrict__ mu2, const float* __restrict__ va2,
    int8_t* __restrict__ wf1, int8_t* __restrict__ wf2,
    float* __restrict__ bnp) {
    int t = blockIdx.x * 256 + threadIdx.x;
    if (t < 256) {
        int o = t & 127;
        if (t < 128) {
            float inv = g1[o] / sqrtf(va1[o] + 1e-5f);
            bnp[o]       = inv;
            bnp[128 + o] = __fsub_rn(be1[o], __fmul_rn(mu1[o], inv));
        } else {
            float inv = g2[o] / sqrtf(va2[o] + 1e-5f);
            bnp[256 + o] = inv;
            bnp[384 + o] = __fsub_rn(be2[o], __fmul_rn(mu2[o], inv));
        }
    }
    if (t >= 2 * 18 * 8 * 64) return;
    int lane = t & 63;
    int nsub = (t >> 6) & 7;
    int kh   = (t >> 9) & 1;
    int tap  = (t >> 10) % 9;
    int which = (t >> 10) / 9;
    const float* w = which ? w2 : w1;
    int8_t* wf = which ? wf2 : wf1;
    int o = (lane & 15) * 8 + nsub;          // lane-contiguous O mapping
    int cbase = kh * 64 + (lane >> 4) * 16;
    int r = tap / 3, s = tap % 3;
    int8_t frag[16];
#pragma unroll
    for (int j = 0; j < 16; ++j) {
        float f = w[((size_t)(o * C + cbase + j) * 3 + r) * 3 + s];
        frag[j] = (int8_t)((f > 0.f) - (f < 0.f));
    }
    *(v4i*)(wf + (size_t)(((tap * 2 + kh) * 8 + nsub) * 64 + lane) * 16) =
        *(const v4i*)frag;
}

// ---------------------------------------------------------------------------
// Persistent binary conv. Grid = 256 blocks (1/CU, LDS-limited), 4 waves.
// All 18*8KB weights staged to LDS once. XCD-swizzled grid-stride over 784
// 256-row tiles (xcd = bid&7 works tiles [xcd*98, xcd*98+98)).
// Wave owns 64 rows (4 rg x 8 O-tiles = 32 accs, 128 VGPRs; launch_bounds
// (256,1) -> 512-reg budget, no spill). K-loop: 18 steps, per step
// 8 ds_read_b128 + 32 MFMAs + 4 A-prefetch loads. No barriers in the loop.
// PHASE 1: sign(BN1(conv)) -> padded NHWC int8 (8 contiguous bytes/lane).
// PHASE 2: clip(BN2(conv) + residual, -1, 1) -> NCHW fp32 (float4 I/O).
template <int PHASE>
__global__ __launch_bounds__(256, 1) void conv_bin(
    const int8_t* __restrict__ xs,
    const int8_t* __restrict__ wf,
    const float* __restrict__ bnp,
    const float* __restrict__ xres,
    int8_t* __restrict__ xs_next,
    float* __restrict__ out)
{
    __shared__ int8_t wlds[18 * 8192];       // 147,456 B (gfx950: 160K/WG)
    int t = threadIdx.x, lane = t & 63, wv = t >> 6;
    int quad = lane >> 4, l15 = lane & 15;

    // one-time weight staging
    {
        const v4i* g = (const v4i*)wf;
        v4i* l = (v4i*)wlds;
        for (int i = t; i < 18 * 512; i += 256) l[i] = g[i];
    }
    // BN params for this lane's 8 contiguous output channels o = l15*8+n
    float binv[8], btt[8];
    {
        int o0 = (PHASE == 1 ? 0 : 256) + l15 * 8;
        int o1 = (PHASE == 1 ? 128 : 384) + l15 * 8;
#pragma unroll
        for (int n = 0; n < 8; ++n) { binv[n] = bnp[o0 + n]; btt[n] = bnp[o1 + n]; }
    }
    __syncthreads();

    int xcd = blockIdx.x & 7, local = blockIdx.x >> 3;   // 32 blocks per XCD
    for (int tloc = local; tloc < TPX; tloc += 32) {
        int tile = xcd * TPX + tloc;
        int mwave = tile * 256 + wv * 64;
        int abase[4];
#pragma unroll
        for (int rg = 0; rg < 4; ++rg) {
            int ma = mwave + rg * 16 + l15;
            int wa = ma % W; int ta = ma / W; int ha = ta % H; int ba = ta / H;
            abase[rg] = ((ba * HP + ha) * WP + wa) * C + quad * 16;
        }

        v4i acc[4][8];
#pragma unroll
        for (int rg = 0; rg < 4; ++rg)
#pragma unroll
            for (int n = 0; n < 8; ++n) acc[rg][n] = (v4i)0;

        v4i a[4];
#pragma unroll
        for (int rg = 0; rg < 4; ++rg) a[rg] = *(const v4i*)(xs + abase[rg]);

#pragma unroll
        for (int step = 0; step < 18; ++step) {
            v4i an[4];
            if (step + 1 < 18) {
                int nt = (step + 1) >> 1, nk = (step + 1) & 1;
                int aoff = ((nt / 3) * WP + (nt % 3)) * C + nk * 64;
#pragma unroll
                for (int rg = 0; rg < 4; ++rg)
                    an[rg] = *(const v4i*)(xs + abase[rg] + aoff);
            }
            const int8_t* lb = wlds + step * 8192;
#pragma unroll
            for (int n = 0; n < 8; ++n) {
                v4i bf = *(const v4i*)(lb + ((n * 64 + lane) << 4));
#pragma unroll
                for (int rg = 0; rg < 4; ++rg)
                    acc[rg][n] = __builtin_amdgcn_mfma_i32_16x16x64_i8(
                        a[rg], bf, acc[rg][n], 0, 0, 0);
            }
            if (step + 1 < 18) {
#pragma unroll
                for (int rg = 0; rg < 4; ++rg) a[rg] = an[rg];
            }
        }

        // Epilogue. D layout: col = l15 (-> o = l15*8+n), row = quad*4 + i.
#pragma unroll
        for (int rg = 0; rg < 4; ++rg) {
            int m0 = mwave + rg * 16 + quad * 4;     // multiple of 4; W%4==0
            int w0 = m0 % W; int t0 = m0 / W; int h0 = t0 % H; int b0 = t0 / H;
            if (PHASE == 1) {
                int base = ((b0 * HP + h0 + 1) * WP + (w0 + 1)) * C + l15 * 8;
#pragma unroll
                for (int i = 0; i < 4; ++i) {
                    uint32_t lo = 0, hi = 0;
#pragma unroll
                    for (int n = 0; n < 8; ++n) {
                        float y = __fadd_rn(__fmul_rn((float)acc[rg][n][i], binv[n]), btt[n]);
                        uint32_t sb = (uint8_t)(int8_t)((y > 0.f) - (y < 0.f));
                        if (n < 4) lo |= sb << (8 * n);
                        else       hi |= sb << (8 * (n - 4));
                    }
                    v2u pk; pk[0] = lo; pk[1] = hi;
                    *(v2u*)(xs_next + base + i * C) = pk;
                }
            } else {
                int pixb = b0 * C * PIX + h0 * W + w0;
#pragma unroll
                for (int n = 0; n < 8; ++n) {
                    int idx = pixb + (l15 * 8 + n) * PIX;
                    v4f r = *(const v4f*)(xres + idx);
                    v4f z;
#pragma unroll
                    for (int i = 0; i < 4; ++i) {
                        float y = __fadd_rn(__fmul_rn((float)acc[rg][n][i], binv[n]), btt[n]);
                        float v = __fadd_rn(y, r[i]);
                        z[i] = fminf(fmaxf(v, -1.f), 1.f);
                    }
                    *(v4f*)(out + idx) = z;
                }
            }
        }
    }
}

// ---------------------------------------------------------------------------
extern "C" void kernel_launch(void* const* d_in, const int* in_sizes, int n_in,
                              void* d_out, int out_size, void* d_ws, size_t ws_size,
                              hipStream_t stream) {
    const float* x   = (const float*)d_in[0];
    const float* w1  = (const float*)d_in[1];
    const float* w2  = (const float*)d_in[2];
    const float* g1  = (const float*)d_in[3];
    const float* be1 = (const float*)d_in[4];
    const float* mu1 = (const float*)d_in[5];
    const float* va1 = (const float*)d_in[6];
    const float* g2  = (const float*)d_in[7];
    const float* be2 = (const float*)d_in[8];
    const float* mu2 = (const float*)d_in[9];
    const float* va2 = (const float*)d_in[10];

    int8_t* ws  = (int8_t*)d_ws;
    int8_t* xs1 = ws + XS1_OFF;
    int8_t* xs2 = ws + XS2_OFF;
    int8_t* wf1 = ws + WF1_OFF;
    int8_t* wf2 = ws + WF2_OFF;
    float*  bnp = (float*)(ws + BNP_OFF);

    zero_halo<<<B, 256, 0, stream>>>(xs1, xs2);
    prep_x<<<M / 256, 256, 0, stream>>>(x, xs1);
    prep_w<<<(2 * 18 * 8 * 64 + 255) / 256, 256, 0, stream>>>(
        w1, w2, g1, be1, mu1, va1, g2, be2, mu2, va2, wf1, wf2, bnp);

    conv_bin<1><<<256, 256, 0, stream>>>(xs1, wf1, bnp, nullptr, xs2, nullptr);
    conv_bin<2><<<256, 256, 0, stream>>>(xs2, wf2, bnp, x, nullptr, (float*)d_out);
}

// Round 5
// 533.996 us; speedup vs baseline: 1.0359x; 1.0092x over previous
//
#include <hip/hip_runtime.h>
#include <cstdint>
#include <cstddef>

// Binarized basic block on MI355X.
// |acc| <= 9*128 = 1152 < THRESH=8000, so the per-partial-sum clip never
// binds -> both convs are exact int convolutions of sign() values.
// int8 implicit GEMM via mfma_i32_16x16x64_i8; all float ops bit-exact vs
// numpy fp32 (explicit __fmul_rn/__fadd_rn, no FMA contraction).
//
// R5: R4 structure (persistent blocks, ALL 144KB weights LDS-resident,
// barrier-free K-loop, contiguous-O full-line stores, XCD-local tiles) but
// rg=2 (32 rows/wave, acc[2][8] = 64 VGPRs). R3/R4's acc[4][8]=128 regs +
// prefetch blew the 256 architected-VGPR cap -> ~190 MB/conv scratch spill
// traffic (R2 with acc[2][8] compiled to VGPR=72, zero spill). LDS pipe
// (32 ds_read_b128/step/CU ~384cyc) vs MFMA (16/wave ~326cyc) -> ~18us/conv
// compute floor; conv2 is HBM-bound (~230MB) anyway.

typedef int      v4i __attribute__((ext_vector_type(4)));
typedef float    v4f __attribute__((ext_vector_type(4)));
typedef unsigned int v2u __attribute__((ext_vector_type(2)));

constexpr int B = 64, C = 128, H = 56, W = 56;
constexpr int HP = H + 2, WP = W + 2;      // zero-padded spatial
constexpr int PIX = H * W;                 // 3136
constexpr int M = B * H * W;               // 200704 = 1568 * 128
constexpr int NTILES = M / 128;            // 1568 tiles of 128 rows
constexpr int TPX = NTILES / 8;            // 196 tiles per XCD

// workspace layout (bytes)
constexpr size_t XS_BYTES = (size_t)B * HP * WP * C;   // 27,557,888
constexpr size_t XS1_OFF = 0;
constexpr size_t XS2_OFF = XS_BYTES;
constexpr size_t WF_BYTES = 18 * 8192;                 // 147,456
constexpr size_t WF1_OFF = 2 * XS_BYTES;
constexpr size_t WF2_OFF = WF1_OFF + WF_BYTES;
constexpr size_t BNP_OFF = WF2_OFF + WF_BYTES;         // 4*128 floats

// ---------------------------------------------------------------------------
// Zero only the padded halos of xs1/xs2 (interiors are fully overwritten).
__global__ __launch_bounds__(256) void zero_halo(int8_t* __restrict__ xs1,
                                                 int8_t* __restrict__ xs2) {
    int b = blockIdx.x;
    int t = threadIdx.x;
    size_t ib = (size_t)b * HP * WP * C;
#pragma unroll
    for (int a = 0; a < 2; ++a) {
        uint32_t* p = (uint32_t*)((a ? xs2 : xs1) + ib);
        const int ROWD = WP * C / 4;             // 1856 dwords per padded row
        for (int i = t; i < ROWD; i += 256) {
            p[i] = 0;
            p[(HP - 1) * ROWD + i] = 0;
        }
        for (int i = t; i < 56 * 2 * 32; i += 256) {
            int r = i >> 6;
            int side = (i >> 5) & 1;
            int j = i & 31;
            p[((r + 1) * WP + side * (WP - 1)) * (C / 4) + j] = 0;
        }
    }
}

// ---------------------------------------------------------------------------
// sign(x) -> padded NHWC int8, via LDS transpose so global stores are
// 16 B/lane full-line. Block = 256 threads = 256 pixels.
__global__ __launch_bounds__(256) void prep_x(const float* __restrict__ x,
                                              int8_t* __restrict__ xs) {
    __shared__ uint32_t tl[256 * 33];   // +1 dword pad -> conflict-free writes
    int t = threadIdx.x;
    int m = blockIdx.x * 256 + t;
    int b_ = m / PIX, hw = m % PIX;
    const float* xp = x + (size_t)b_ * C * PIX + hw;
#pragma unroll
    for (int c4 = 0; c4 < 32; ++c4) {
        uint32_t v = 0;
#pragma unroll
        for (int j = 0; j < 4; ++j) {
            float f = xp[(size_t)(c4 * 4 + j) * PIX];
            v |= ((uint32_t)(uint8_t)(int8_t)((f > 0.f) - (f < 0.f))) << (8 * j);
        }
        tl[t * 33 + c4] = v;
    }
    __syncthreads();
    int pl = t >> 3, co = t & 7;        // 8 threads per pixel, 16 B each
#pragma unroll
    for (int pass = 0; pass < 8; ++pass) {
        int p = pass * 32 + pl;
        int mg = blockIdx.x * 256 + p;
        int b2 = mg / PIX, hw2 = mg % PIX, h2 = hw2 / W, w2 = hw2 % W;
        size_t ob = ((size_t)(b2 * HP + h2 + 1) * WP + (w2 + 1)) * C + co * 16;
        v4i val;
#pragma unroll
        for (int k = 0; k < 4; ++k) val[k] = (int)tl[p * 33 + co * 4 + k];
        *(v4i*)(xs + ob) = val;
    }
}

// ---------------------------------------------------------------------------
// Binarize weights into MFMA B-fragment order with o = col*8 + n:
//   wf[((tap*2+kh)*8+n)*1024 + lane*16 + j] =
//     sign(w[o=(lane&15)*8+n][c=kh*64+(lane>>4)*16+j][r][s])
// Also BN inv/shift tables exactly as numpy fp32.
__global__ __launch_bounds__(256) void prep_w(
    const float* __restrict__ w1, const float* __restrict__ w2,
    const float* __restrict__ g1, const float* __restrict__ be1,
    const float* __restrict__ mu1, const float* __restrict__ va1,
    const float* __restrict__ g2, const float* __restrict__ be2,
    const float* __restrict__ mu2, const float* __restrict__ va2,
    int8_t* __restrict__ wf1, int8_t* __restrict__ wf2,
    float* __restrict__ bnp) {
    int t = blockIdx.x * 256 + threadIdx.x;
    if (t < 256) {
        int o = t & 127;
        if (t < 128) {
            float inv = g1[o] / sqrtf(va1[o] + 1e-5f);
            bnp[o]       = inv;
            bnp[128 + o] = __fsub_rn(be1[o], __fmul_rn(mu1[o], inv));
        } else {
            float inv = g2[o] / sqrtf(va2[o] + 1e-5f);
            bnp[256 + o] = inv;
            bnp[384 + o] = __fsub_rn(be2[o], __fmul_rn(mu2[o], inv));
        }
    }
    if (t >= 2 * 18 * 8 * 64) return;
    int lane = t & 63;
    int nsub = (t >> 6) & 7;
    int kh   = (t >> 9) & 1;
    int tap  = (t >> 10) % 9;
    int which = (t >> 10) / 9;
    const float* w = which ? w2 : w1;
    int8_t* wf = which ? wf2 : wf1;
    int o = (lane & 15) * 8 + nsub;          // lane-contiguous O mapping
    int cbase = kh * 64 + (lane >> 4) * 16;
    int r = tap / 3, s = tap % 3;
    int8_t frag[16];
#pragma unroll
    for (int j = 0; j < 16; ++j) {
        float f = w[((size_t)(o * C + cbase + j) * 3 + r) * 3 + s];
        frag[j] = (int8_t)((f > 0.f) - (f < 0.f));
    }
    *(v4i*)(wf + (size_t)(((tap * 2 + kh) * 8 + nsub) * 64 + lane) * 16) =
        *(const v4i*)frag;
}

// ---------------------------------------------------------------------------
// Persistent binary conv. Grid = 256 blocks (1/CU, LDS-limited), 4 waves.
// All 18*8KB weights staged to LDS once. XCD-swizzled grid-stride over 1568
// 128-row tiles (xcd = bid&7 works tiles [xcd*196, xcd*196+196)).
// Wave owns 32 rows (2 rg x 8 O-tiles = 64 acc VGPRs -> no spill; R3/R4's
// 128 acc VGPRs hit the 256 architected cap and spilled ~190MB/conv).
// K-loop: 18 steps, per step 8 ds_read_b128 + 16 MFMAs + 2 A-prefetch loads.
// No barriers, no global weight traffic in the loop.
// PHASE 1: sign(BN1(conv)) -> padded NHWC int8 (8 contiguous bytes/lane).
// PHASE 2: clip(BN2(conv) + residual, -1, 1) -> NCHW fp32 (float4 I/O).
template <int PHASE>
__global__ __launch_bounds__(256, 1) void conv_bin(
    const int8_t* __restrict__ xs,
    const int8_t* __restrict__ wf,
    const float* __restrict__ bnp,
    const float* __restrict__ xres,
    int8_t* __restrict__ xs_next,
    float* __restrict__ out)
{
    __shared__ int8_t wlds[18 * 8192];       // 147,456 B (gfx950: 160K/WG)
    int t = threadIdx.x, lane = t & 63, wv = t >> 6;
    int quad = lane >> 4, l15 = lane & 15;

    // one-time weight staging
    {
        const v4i* g = (const v4i*)wf;
        v4i* l = (v4i*)wlds;
        for (int i = t; i < 18 * 512; i += 256) l[i] = g[i];
    }
    // BN params for this lane's 8 contiguous output channels o = l15*8+n
    float binv[8], btt[8];
    {
        int o0 = (PHASE == 1 ? 0 : 256) + l15 * 8;
        int o1 = (PHASE == 1 ? 128 : 384) + l15 * 8;
#pragma unroll
        for (int n = 0; n < 8; ++n) { binv[n] = bnp[o0 + n]; btt[n] = bnp[o1 + n]; }
    }
    __syncthreads();

    int xcd = blockIdx.x & 7, local = blockIdx.x >> 3;   // 32 blocks per XCD
    for (int tloc = local; tloc < TPX; tloc += 32) {
        int tile = xcd * TPX + tloc;
        int mwave = tile * 128 + wv * 32;
        int abase[2];
#pragma unroll
        for (int rg = 0; rg < 2; ++rg) {
            int ma = mwave + rg * 16 + l15;
            int wa = ma % W; int ta = ma / W; int ha = ta % H; int ba = ta / H;
            abase[rg] = ((ba * HP + ha) * WP + wa) * C + quad * 16;
        }

        v4i acc[2][8];
#pragma unroll
        for (int rg = 0; rg < 2; ++rg)
#pragma unroll
            for (int n = 0; n < 8; ++n) acc[rg][n] = (v4i)0;

        v4i a[2];
#pragma unroll
        for (int rg = 0; rg < 2; ++rg) a[rg] = *(const v4i*)(xs + abase[rg]);

#pragma unroll
        for (int step = 0; step < 18; ++step) {
            v4i an[2];
            if (step + 1 < 18) {
                int nt = (step + 1) >> 1, nk = (step + 1) & 1;
                int aoff = ((nt / 3) * WP + (nt % 3)) * C + nk * 64;
#pragma unroll
                for (int rg = 0; rg < 2; ++rg)
                    an[rg] = *(const v4i*)(xs + abase[rg] + aoff);
            }
            const int8_t* lb = wlds + step * 8192;
#pragma unroll
            for (int n = 0; n < 8; ++n) {
                v4i bf = *(const v4i*)(lb + ((n * 64 + lane) << 4));
#pragma unroll
                for (int rg = 0; rg < 2; ++rg)
                    acc[rg][n] = __builtin_amdgcn_mfma_i32_16x16x64_i8(
                        a[rg], bf, acc[rg][n], 0, 0, 0);
            }
            if (step + 1 < 18) {
#pragma unroll
                for (int rg = 0; rg < 2; ++rg) a[rg] = an[rg];
            }
        }

        // Epilogue. D layout: col = l15 (-> o = l15*8+n), row = quad*4 + i.
#pragma unroll
        for (int rg = 0; rg < 2; ++rg) {
            int m0 = mwave + rg * 16 + quad * 4;     // multiple of 4; W%4==0
            int w0 = m0 % W; int t0 = m0 / W; int h0 = t0 % H; int b0 = t0 / H;
            if (PHASE == 1) {
                int base = ((b0 * HP + h0 + 1) * WP + (w0 + 1)) * C + l15 * 8;
#pragma unroll
                for (int i = 0; i < 4; ++i) {
                    uint32_t lo = 0, hi = 0;
#pragma unroll
                    for (int n = 0; n < 8; ++n) {
                        float y = __fadd_rn(__fmul_rn((float)acc[rg][n][i], binv[n]), btt[n]);
                        uint32_t sb = (uint8_t)(int8_t)((y > 0.f) - (y < 0.f));
                        if (n < 4) lo |= sb << (8 * n);
                        else       hi |= sb << (8 * (n - 4));
                    }
                    v2u pk; pk[0] = lo; pk[1] = hi;
                    *(v2u*)(xs_next + base + i * C) = pk;
                }
            } else {
                int pixb = b0 * C * PIX + h0 * W + w0;
#pragma unroll
                for (int n = 0; n < 8; ++n) {
                    int idx = pixb + (l15 * 8 + n) * PIX;
                    v4f r = *(const v4f*)(xres + idx);
                    v4f z;
#pragma unroll
                    for (int i = 0; i < 4; ++i) {
                        float y = __fadd_rn(__fmul_rn((float)acc[rg][n][i], binv[n]), btt[n]);
                        float v = __fadd_rn(y, r[i]);
                        z[i] = fminf(fmaxf(v, -1.f), 1.f);
                    }
                    *(v4f*)(out + idx) = z;
                }
            }
        }
    }
}

// ---------------------------------------------------------------------------
extern "C" void kernel_launch(void* const* d_in, const int* in_sizes, int n_in,
                              void* d_out, int out_size, void* d_ws, size_t ws_size,
                              hipStream_t stream) {
    const float* x   = (const float*)d_in[0];
    const float* w1  = (const float*)d_in[1];
    const float* w2  = (const float*)d_in[2];
    const float* g1  = (const float*)d_in[3];
    const float* be1 = (const float*)d_in[4];
    const float* mu1 = (const float*)d_in[5];
    const float* va1 = (const float*)d_in[6];
    const float* g2  = (const float*)d_in[7];
    const float* be2 = (const float*)d_in[8];
    const float* mu2 = (const float*)d_in[9];
    const float* va2 = (const float*)d_in[10];

    int8_t* ws  = (int8_t*)d_ws;
    int8_t* xs1 = ws + XS1_OFF;
    int8_t* xs2 = ws + XS2_OFF;
    int8_t* wf1 = ws + WF1_OFF;
    int8_t* wf2 = ws + WF2_OFF;
    float*  bnp = (float*)(ws + BNP_OFF);

    zero_halo<<<B, 256, 0, stream>>>(xs1, xs2);
    prep_x<<<M / 256, 256, 0, stream>>>(x, xs1);
    prep_w<<<(2 * 18 * 8 * 64 + 255) / 256, 256, 0, stream>>>(
        w1, w2, g1, be1, mu1, va1, g2, be2, mu2, va2, wf1, wf2, bnp);

    conv_bin<1><<<256, 256, 0, stream>>>(xs1, wf1, bnp, nullptr, xs2, nullptr);
    conv_bin<2><<<256, 256, 0, stream>>>(xs2, wf2, bnp, x, nullptr, (float*)d_out);
}

// Round 6
// 350.920 us; speedup vs baseline: 1.5764x; 1.5217x over previous
//
#include <hip/hip_runtime.h>
#include <cstdint>
#include <cstddef>

// Binarized basic block on MI355X.
// |acc| <= 9*128 = 1152 < THRESH=8000, so the per-partial-sum clip never
// binds -> both convs are exact int convolutions of sign() values.
// int8 implicit GEMM via mfma_i32_16x16x64_i8; all float ops bit-exact vs
// numpy fp32 (explicit __fmul_rn/__fadd_rn, no FMA contraction).
//
// R6: root cause of R3-R5's 256-VGPR spills found: full unroll of the
// barrier-free 18-step K-loop let the compiler hoist ALL 17 steps' A-prefetch
// loads (136 VGPRs) -> acc spilled to scratch (~400 MB/conv traffic).
// Fix: #pragma unroll 1 on the K-loop (loop body carries only a[2]/an[2] +
// 8 bf temps + 64 acc ~= 130 regs). Also 512-thread blocks (2 waves/SIMD) so
// paired waves hide each other's LDS/global latency. Weights stay fully
// LDS-resident (144 KB); contiguous-O full-line stores; XCD-local tiles.

typedef int      v4i __attribute__((ext_vector_type(4)));
typedef float    v4f __attribute__((ext_vector_type(4)));
typedef unsigned int v2u __attribute__((ext_vector_type(2)));

constexpr int B = 64, C = 128, H = 56, W = 56;
constexpr int HP = H + 2, WP = W + 2;      // zero-padded spatial
constexpr int PIX = H * W;                 // 3136
constexpr int M = B * H * W;               // 200704 = 784 * 256
constexpr int NTILES = M / 256;            // 784 tiles of 256 rows
constexpr int TPX = NTILES / 8;            // 98 tiles per XCD

// workspace layout (bytes)
constexpr size_t XS_BYTES = (size_t)B * HP * WP * C;   // 27,557,888
constexpr size_t XS1_OFF = 0;
constexpr size_t XS2_OFF = XS_BYTES;
constexpr size_t WF_BYTES = 18 * 8192;                 // 147,456
constexpr size_t WF1_OFF = 2 * XS_BYTES;
constexpr size_t WF2_OFF = WF1_OFF + WF_BYTES;
constexpr size_t BNP_OFF = WF2_OFF + WF_BYTES;         // 4*128 floats

// ---------------------------------------------------------------------------
// Zero only the padded halos of xs1/xs2 (interiors are fully overwritten).
__global__ __launch_bounds__(256) void zero_halo(int8_t* __restrict__ xs1,
                                                 int8_t* __restrict__ xs2) {
    int b = blockIdx.x;
    int t = threadIdx.x;
    size_t ib = (size_t)b * HP * WP * C;
#pragma unroll
    for (int a = 0; a < 2; ++a) {
        uint32_t* p = (uint32_t*)((a ? xs2 : xs1) + ib);
        const int ROWD = WP * C / 4;             // 1856 dwords per padded row
        for (int i = t; i < ROWD; i += 256) {
            p[i] = 0;
            p[(HP - 1) * ROWD + i] = 0;
        }
        for (int i = t; i < 56 * 2 * 32; i += 256) {
            int r = i >> 6;
            int side = (i >> 5) & 1;
            int j = i & 31;
            p[((r + 1) * WP + side * (WP - 1)) * (C / 4) + j] = 0;
        }
    }
}

// ---------------------------------------------------------------------------
// sign(x) -> padded NHWC int8, via LDS transpose so global stores are
// 16 B/lane full-line. Block = 256 threads = 256 pixels.
__global__ __launch_bounds__(256) void prep_x(const float* __restrict__ x,
                                              int8_t* __restrict__ xs) {
    __shared__ uint32_t tl[256 * 33];   // +1 dword pad -> conflict-free writes
    int t = threadIdx.x;
    int m = blockIdx.x * 256 + t;
    int b_ = m / PIX, hw = m % PIX;
    const float* xp = x + (size_t)b_ * C * PIX + hw;
#pragma unroll
    for (int c4 = 0; c4 < 32; ++c4) {
        uint32_t v = 0;
#pragma unroll
        for (int j = 0; j < 4; ++j) {
            float f = xp[(size_t)(c4 * 4 + j) * PIX];
            v |= ((uint32_t)(uint8_t)(int8_t)((f > 0.f) - (f < 0.f))) << (8 * j);
        }
        tl[t * 33 + c4] = v;
    }
    __syncthreads();
    int pl = t >> 3, co = t & 7;        // 8 threads per pixel, 16 B each
#pragma unroll
    for (int pass = 0; pass < 8; ++pass) {
        int p = pass * 32 + pl;
        int mg = blockIdx.x * 256 + p;
        int b2 = mg / PIX, hw2 = mg % PIX, h2 = hw2 / W, w2 = hw2 % W;
        size_t ob = ((size_t)(b2 * HP + h2 + 1) * WP + (w2 + 1)) * C + co * 16;
        v4i val;
#pragma unroll
        for (int k = 0; k < 4; ++k) val[k] = (int)tl[p * 33 + co * 4 + k];
        *(v4i*)(xs + ob) = val;
    }
}

// ---------------------------------------------------------------------------
// Binarize weights into MFMA B-fragment order with o = col*8 + n:
//   wf[((tap*2+kh)*8+n)*1024 + lane*16 + j] =
//     sign(w[o=(lane&15)*8+n][c=kh*64+(lane>>4)*16+j][r][s])
// Also BN inv/shift tables exactly as numpy fp32.
__global__ __launch_bounds__(256) void prep_w(
    const float* __restrict__ w1, const float* __restrict__ w2,
    const float* __restrict__ g1, const float* __restrict__ be1,
    const float* __restrict__ mu1, const float* __restrict__ va1,
    const float* __restrict__ g2, const float* __restrict__ be2,
    const float* __restrict__ mu2, const float* __restrict__ va2,
    int8_t* __restrict__ wf1, int8_t* __restrict__ wf2,
    float* __restrict__ bnp) {
    int t = blockIdx.x * 256 + threadIdx.x;
    if (t < 256) {
        int o = t & 127;
        if (t < 128) {
            float inv = g1[o] / sqrtf(va1[o] + 1e-5f);
            bnp[o]       = inv;
            bnp[128 + o] = __fsub_rn(be1[o], __fmul_rn(mu1[o], inv));
        } else {
            float inv = g2[o] / sqrtf(va2[o] + 1e-5f);
            bnp[256 + o] = inv;
            bnp[384 + o] = __fsub_rn(be2[o], __fmul_rn(mu2[o], inv));
        }
    }
    if (t >= 2 * 18 * 8 * 64) return;
    int lane = t & 63;
    int nsub = (t >> 6) & 7;
    int kh   = (t >> 9) & 1;
    int tap  = (t >> 10) % 9;
    int which = (t >> 10) / 9;
    const float* w = which ? w2 : w1;
    int8_t* wf = which ? wf2 : wf1;
    int o = (lane & 15) * 8 + nsub;          // lane-contiguous O mapping
    int cbase = kh * 64 + (lane >> 4) * 16;
    int r = tap / 3, s = tap % 3;
    int8_t frag[16];
#pragma unroll
    for (int j = 0; j < 16; ++j) {
        float f = w[((size_t)(o * C + cbase + j) * 3 + r) * 3 + s];
        frag[j] = (int8_t)((f > 0.f) - (f < 0.f));
    }
    *(v4i*)(wf + (size_t)(((tap * 2 + kh) * 8 + nsub) * 64 + lane) * 16) =
        *(const v4i*)frag;
}

// ---------------------------------------------------------------------------
// Persistent binary conv. Grid = 256 blocks (1/CU, LDS-limited), 512 thr =
// 8 waves = 2 waves/SIMD (waves pair-hide each other's latency).
// All 18*8KB weights staged to LDS once. XCD-swizzled grid-stride over 784
// 256-row tiles. Wave owns 32 rows (2 rg x 8 O-tiles = 64 acc VGPRs).
// K-loop: #pragma unroll 1 (CRITICAL: full unroll let the compiler hoist all
// 17 steps' A-prefetches -> 256-VGPR cap -> scratch spills in R3-R5).
// Per step: 8 ds_read_b128 + 16 MFMAs + 2 A-prefetch loads, no barriers.
// PHASE 1: sign(BN1(conv)) -> padded NHWC int8 (8 contiguous bytes/lane).
// PHASE 2: clip(BN2(conv) + residual, -1, 1) -> NCHW fp32 (float4 I/O).
template <int PHASE>
__global__ __launch_bounds__(512, 1) void conv_bin(
    const int8_t* __restrict__ xs,
    const int8_t* __restrict__ wf,
    const float* __restrict__ bnp,
    const float* __restrict__ xres,
    int8_t* __restrict__ xs_next,
    float* __restrict__ out)
{
    __shared__ int8_t wlds[18 * 8192];       // 147,456 B (gfx950: 160K/WG)
    int t = threadIdx.x, lane = t & 63, wv = t >> 6;
    int quad = lane >> 4, l15 = lane & 15;

    // one-time weight staging
    {
        const v4i* g = (const v4i*)wf;
        v4i* l = (v4i*)wlds;
        for (int i = t; i < 18 * 512; i += 512) l[i] = g[i];
    }
    // BN params for this lane's 8 contiguous output channels o = l15*8+n
    float binv[8], btt[8];
    {
        int o0 = (PHASE == 1 ? 0 : 256) + l15 * 8;
        int o1 = (PHASE == 1 ? 128 : 384) + l15 * 8;
#pragma unroll
        for (int n = 0; n < 8; ++n) { binv[n] = bnp[o0 + n]; btt[n] = bnp[o1 + n]; }
    }
    __syncthreads();

    int xcd = blockIdx.x & 7, local = blockIdx.x >> 3;   // 32 blocks per XCD
    for (int tloc = local; tloc < TPX; tloc += 32) {
        int tile = xcd * TPX + tloc;
        int mwave = tile * 256 + wv * 32;
        int abase[2];
#pragma unroll
        for (int rg = 0; rg < 2; ++rg) {
            int ma = mwave + rg * 16 + l15;
            int wa = ma % W; int ta = ma / W; int ha = ta % H; int ba = ta / H;
            abase[rg] = ((ba * HP + ha) * WP + wa) * C + quad * 16;
        }

        v4i acc[2][8];
#pragma unroll
        for (int rg = 0; rg < 2; ++rg)
#pragma unroll
            for (int n = 0; n < 8; ++n) acc[rg][n] = (v4i)0;

        v4i a[2];
#pragma unroll
        for (int rg = 0; rg < 2; ++rg) a[rg] = *(const v4i*)(xs + abase[rg]);

#pragma unroll 1   // DO NOT fully unroll: prevents cross-step load hoisting
        for (int step = 0; step < 18; ++step) {
            v4i an[2];
            if (step + 1 < 18) {
                int nt = (step + 1) >> 1, nk = (step + 1) & 1;
                int aoff = ((nt / 3) * WP + (nt % 3)) * C + nk * 64;
#pragma unroll
                for (int rg = 0; rg < 2; ++rg)
                    an[rg] = *(const v4i*)(xs + abase[rg] + aoff);
            }
            const int8_t* lb = wlds + step * 8192;
#pragma unroll
            for (int n = 0; n < 8; ++n) {
                v4i bf = *(const v4i*)(lb + ((n * 64 + lane) << 4));
#pragma unroll
                for (int rg = 0; rg < 2; ++rg)
                    acc[rg][n] = __builtin_amdgcn_mfma_i32_16x16x64_i8(
                        a[rg], bf, acc[rg][n], 0, 0, 0);
            }
#pragma unroll
            for (int rg = 0; rg < 2; ++rg) a[rg] = an[rg];
        }

        // Epilogue. D layout: col = l15 (-> o = l15*8+n), row = quad*4 + i.
#pragma unroll
        for (int rg = 0; rg < 2; ++rg) {
            int m0 = mwave + rg * 16 + quad * 4;     // multiple of 4; W%4==0
            int w0 = m0 % W; int t0 = m0 / W; int h0 = t0 % H; int b0 = t0 / H;
            if (PHASE == 1) {
                int base = ((b0 * HP + h0 + 1) * WP + (w0 + 1)) * C + l15 * 8;
#pragma unroll
                for (int i = 0; i < 4; ++i) {
                    uint32_t lo = 0, hi = 0;
#pragma unroll
                    for (int n = 0; n < 8; ++n) {
                        float y = __fadd_rn(__fmul_rn((float)acc[rg][n][i], binv[n]), btt[n]);
                        uint32_t sb = (uint8_t)(int8_t)((y > 0.f) - (y < 0.f));
                        if (n < 4) lo |= sb << (8 * n);
                        else       hi |= sb << (8 * (n - 4));
                    }
                    v2u pk; pk[0] = lo; pk[1] = hi;
                    *(v2u*)(xs_next + base + i * C) = pk;
                }
            } else {
                int pixb = b0 * C * PIX + h0 * W + w0;
#pragma unroll
                for (int n = 0; n < 8; ++n) {
                    int idx = pixb + (l15 * 8 + n) * PIX;
                    v4f r = *(const v4f*)(xres + idx);
                    v4f z;
#pragma unroll
                    for (int i = 0; i < 4; ++i) {
                        float y = __fadd_rn(__fmul_rn((float)acc[rg][n][i], binv[n]), btt[n]);
                        float v = __fadd_rn(y, r[i]);
                        z[i] = fminf(fmaxf(v, -1.f), 1.f);
                    }
                    *(v4f*)(out + idx) = z;
                }
            }
        }
    }
}

// ---------------------------------------------------------------------------
extern "C" void kernel_launch(void* const* d_in, const int* in_sizes, int n_in,
                              void* d_out, int out_size, void* d_ws, size_t ws_size,
                              hipStream_t stream) {
    const float* x   = (const float*)d_in[0];
    const float* w1  = (const float*)d_in[1];
    const float* w2  = (const float*)d_in[2];
    const float* g1  = (const float*)d_in[3];
    const float* be1 = (const float*)d_in[4];
    const float* mu1 = (const float*)d_in[5];
    const float* va1 = (const float*)d_in[6];
    const float* g2  = (const float*)d_in[7];
    const float* be2 = (const float*)d_in[8];
    const float* mu2 = (const float*)d_in[9];
    const float* va2 = (const float*)d_in[10];

    int8_t* ws  = (int8_t*)d_ws;
    int8_t* xs1 = ws + XS1_OFF;
    int8_t* xs2 = ws + XS2_OFF;
    int8_t* wf1 = ws + WF1_OFF;
    int8_t* wf2 = ws + WF2_OFF;
    float*  bnp = (float*)(ws + BNP_OFF);

    zero_halo<<<B, 256, 0, stream>>>(xs1, xs2);
    prep_x<<<M / 256, 256, 0, stream>>>(x, xs1);
    prep_w<<<(2 * 18 * 8 * 64 + 255) / 256, 256, 0, stream>>>(
        w1, w2, g1, be1, mu1, va1, g2, be2, mu2, va2, wf1, wf2, bnp);

    conv_bin<1><<<256, 512, 0, stream>>>(xs1, wf1, bnp, nullptr, xs2, nullptr);
    conv_bin<2><<<256, 512, 0, stream>>>(xs2, wf2, bnp, x, nullptr, (float*)d_out);
}